// Round 4
// baseline (265.181 us; speedup 1.0000x reference)
//
#include <hip/hip_runtime.h>
#include <math.h>

typedef __attribute__((ext_vector_type(8))) short short8;
typedef __bf16 bf16x8 __attribute__((ext_vector_type(8)));
typedef __attribute__((ext_vector_type(4))) float f32x4;
typedef __attribute__((ext_vector_type(2))) float f32x2;
typedef __attribute__((ext_vector_type(16))) float f32x16;
typedef __attribute__((ext_vector_type(4))) unsigned uint4v;

__device__ inline short f2bf(float f) {
    unsigned u = __builtin_bit_cast(unsigned, f);
    u += 0x7fff + ((u >> 16) & 1);   // round-to-nearest-even
    return (short)(u >> 16);
}
__device__ inline float bf2f(short h) {
    return __builtin_bit_cast(float, ((unsigned)(unsigned short)h) << 16);
}
__device__ inline float gelu_f(float x) {
    return 0.5f * x * (1.f + erff(x * 0.70710678118654752f));
}

// ---------------------------------------------------------------------------
// Fused prep: input casts (blocks 0..6143) + all 6 weight transposes
// (blocks 6144..8191, all plain bf16 [N][K]). Block-uniform branches.
// ---------------------------------------------------------------------------
__global__ __launch_bounds__(256) void prep_all(
    const float* __restrict__ q, const float* __restrict__ k,
    const float* __restrict__ v,
    short* __restrict__ qc, short* __restrict__ kc, short* __restrict__ vc,
    const float* __restrict__ Wq1, const float* __restrict__ Wk1,
    const float* __restrict__ Wq2, const float* __restrict__ Wk2,
    const float* __restrict__ Wv,  const float* __restrict__ Wo,
    short* __restrict__ Wq1t, short* __restrict__ Wk1t,
    short* __restrict__ Wq2t, short* __restrict__ Wk2t,
    short* __restrict__ Wvt,  short* __restrict__ Wot)
{
    int id = blockIdx.x;
    if (id < 6144) {
        const float* src = id < 2048 ? q : (id < 4096 ? k : v);
        short* dst = id < 2048 ? qc : (id < 4096 ? kc : vc);
        int blk = id & 2047;
        size_t i = ((size_t)blk * 256 + threadIdx.x) * 8;
        float4 a = *(const float4*)(src + i);
        float4 b = *(const float4*)(src + i + 4);
        short8 o;
        o[0] = f2bf(a.x); o[1] = f2bf(a.y); o[2] = f2bf(a.z); o[3] = f2bf(a.w);
        o[4] = f2bf(b.x); o[5] = f2bf(b.y); o[6] = f2bf(b.z); o[7] = f2bf(b.w);
        *(short8*)(void*)(dst + i) = o;
        return;
    }
    id -= 6144;
    const float* W; short* Wt; int K, N;
    if (id < 512)       { W = Wq1; Wt = Wq1t; K = 512;  N = 1024; }
    else if (id < 1024) { W = Wk1; Wt = Wk1t; K = 512;  N = 1024; id -= 512; }
    else if (id < 1280) { W = Wq2; Wt = Wq2t; K = 1024; N = 256;  id -= 1024; }
    else if (id < 1536) { W = Wk2; Wt = Wk2t; K = 1024; N = 256;  id -= 1280; }
    else if (id < 1792) { W = Wv;  Wt = Wvt;  K = 512;  N = 512;  id -= 1536; }
    else                { W = Wo;  Wt = Wot;  K = 512;  N = 512;  id -= 1792; }
    int nx = N >> 5;
    int n0 = (id % nx) * 32, k0 = (id / nx) * 32;

    __shared__ float T[32][33];
    int tid = threadIdx.x;
    int r = tid >> 3, c4 = (tid & 7) * 4;
    float4 v4 = *(const float4*)&W[(size_t)(k0 + r) * N + n0 + c4];
    T[r][c4 + 0] = v4.x; T[r][c4 + 1] = v4.y; T[r][c4 + 2] = v4.z; T[r][c4 + 3] = v4.w;
    __syncthreads();
    short4 o;
    o.x = f2bf(T[c4 + 0][r]);
    o.y = f2bf(T[c4 + 1][r]);
    o.z = f2bf(T[c4 + 2][r]);
    o.w = f2bf(T[c4 + 3][r]);
    *(short4*)&Wt[(size_t)(n0 + r) * K + k0 + c4] = o;
}

// ---------------------------------------------------------------------------
// bf16 MFMA GEMM, B^T layout, BK=64, XCD-aware swizzle. BM/BN templated:
// BM=128/BN=128 for big GEMMs; BM=64/BN=64 doubles the grid for small-N
// GEMMs (4 blocks/CU = 16 waves/CU, vs 2 blocks/CU at BM=128).
// 4 waves in 2x2; each wave covers BM/2 x BN/2.
// ---------------------------------------------------------------------------
template <int ACT, int OUTF32, int BM, int BN>
__global__ __launch_bounds__(256) void gemm_bt(
    const short* __restrict__ A0, const short* __restrict__ A1,
    const short* __restrict__ B0, const short* __restrict__ B1,
    const float* __restrict__ b0, const float* __restrict__ b1,
    void* C0_, void* C1_,
    float s0, float s1, int nbn, int N, int K)
{
    constexpr int MT = BM / 32;        // m-tiles per wave
    constexpr int NT = BN / 32;        // n-tiles per wave
    const int z = blockIdx.z;
    const short* A = z ? A1 : A0;
    const short* B = z ? B1 : B0;
    const float* bias = z ? b1 : b0;
    void* C_ = z ? C1_ : C0_;
    const float scale = z ? s1 : s0;

    const int L = blockIdx.x;
    const int xcd = L & 7;
    const int per = L >> 3;
    const int bn = (per % nbn) * BN;
    const int bm = ((per / nbn) * 8 + xcd) * BM;

    const int tid = threadIdx.x;
    const int w = tid >> 6;
    const int lane = tid & 63;
    const int l15 = lane & 15, quad = lane >> 4;
    const int wm = (w >> 1) * (BM / 2), wn = (w & 1) * (BN / 2);

    __shared__ __align__(16) short As[BM * 64];
    __shared__ __align__(16) short Bs[BN * 64];

    f32x4 acc[MT][NT];
#pragma unroll
    for (int mt = 0; mt < MT; ++mt)
#pragma unroll
        for (int nt = 0; nt < NT; ++nt) acc[mt][nt] = (f32x4){0.f, 0.f, 0.f, 0.f};

    for (int k0 = 0; k0 < K; k0 += 64) {
#pragma unroll
        for (int i = 0; i < BM / 32; ++i) {
            int ga = tid + i * 256;
            int row = ga >> 3, g = ga & 7;
            short8 aval = *(const short8*)(const void*)&A[(size_t)(bm + row) * K + k0 + g * 8];
            *(short8*)(void*)&As[row * 64 + ((g ^ (row & 7)) * 8)] = aval;
        }
#pragma unroll
        for (int i = 0; i < BN / 32; ++i) {
            int gb = tid + i * 256;
            int row = gb >> 3, g = gb & 7;
            short8 bval = *(const short8*)(const void*)&B[(size_t)(bn + row) * K + k0 + g * 8];
            *(short8*)(void*)&Bs[row * 64 + ((g ^ (row & 7)) * 8)] = bval;
        }
        __syncthreads();

#pragma unroll
        for (int ks = 0; ks < 2; ++ks) {
            bf16x8 af[MT], bfr[NT];
#pragma unroll
            for (int t = 0; t < MT; ++t) {
                int row = wm + t * 16 + l15;
                af[t] = __builtin_bit_cast(bf16x8,
                    *(const short8*)(const void*)&As[row * 64 + (((ks * 4 + quad) ^ (row & 7)) * 8)]);
            }
#pragma unroll
            for (int t = 0; t < NT; ++t) {
                int row = wn + t * 16 + l15;
                bfr[t] = __builtin_bit_cast(bf16x8,
                    *(const short8*)(const void*)&Bs[row * 64 + (((ks * 4 + quad) ^ (row & 7)) * 8)]);
            }
#pragma unroll
            for (int mt = 0; mt < MT; ++mt)
#pragma unroll
                for (int nt = 0; nt < NT; ++nt)
                    acc[mt][nt] = __builtin_amdgcn_mfma_f32_16x16x32_bf16(af[mt], bfr[nt], acc[mt][nt], 0, 0, 0);
        }
        __syncthreads();
    }

    float bv[NT];
#pragma unroll
    for (int nt = 0; nt < NT; ++nt) bv[nt] = bias[bn + wn + nt * 16 + l15];
#pragma unroll
    for (int mt = 0; mt < MT; ++mt)
#pragma unroll
        for (int r = 0; r < 4; ++r) {
            int row = bm + wm + mt * 16 + quad * 4 + r;
#pragma unroll
            for (int nt = 0; nt < NT; ++nt) {
                float v = acc[mt][nt][r] + bv[nt];
                if (ACT) v = gelu_f(v);
                v *= scale;
                int col = bn + wn + nt * 16 + l15;
                if (OUTF32) ((float*)C_)[(size_t)row * N + col] = v;
                else        ((short*)C_)[(size_t)row * N + col] = f2bf(v);
            }
        }
}

// ---------------------------------------------------------------------------
// Fused K+V repack (proven R14). y < 16: K-repack; y >= 16: V-repack.
// ---------------------------------------------------------------------------
__global__ __launch_bounds__(256) void repack_kv(
    const short* __restrict__ kb, short* __restrict__ kfr,
    const short* __restrict__ vbb, short* __restrict__ vfr)
{
    const int kt = blockIdx.x;
    const int y = blockIdx.y;
    const int t = threadIdx.x;
    __shared__ short Vt[64][72];   // [key][dk] (V path only)

    if (y < 16) {
        const int bh = y;
        const int b = bh >> 3, h = bh & 7;
        const int c = t >> 6, l = t & 63;
        const int nt = c >> 1, ks = c & 1;
        int key = kt * 64 + nt * 32 + (l & 31);
        int k = ks * 16 + (l >> 5) * 8;
        short8 v = *(const short8*)(const void*)&kb[(size_t)(b * 4096 + key) * 256 + h * 32 + k];
        *(short8*)(void*)&kfr[((((size_t)bh * 64 + kt) * 4 + c) * 64 + l) * 8] = v;
        return;
    }
    const int bh = y - 16;
    const int b = bh >> 3, h = bh & 7;
#pragma unroll
    for (int it = 0; it < 2; ++it) {
        int idx = t + it * 256;
        int keyr = idx >> 3, c8 = (idx & 7) * 8;
        *(short8*)(void*)&Vt[keyr][c8] =
            *(const short8*)(const void*)&vbb[(size_t)(b * 4096 + kt * 64 + keyr) * 512 + h * 64 + c8];
    }
    __syncthreads();
#pragma unroll
    for (int it = 0; it < 2; ++it) {
        int chunk = (t >> 6) * 2 + it;
        int l = t & 63;
        int dt = chunk >> 2, ks = chunk & 3;
        short8 o;
#pragma unroll
        for (int j = 0; j < 8; ++j)
            o[j] = Vt[ks * 16 + (l >> 5) * 8 + j][dt * 32 + (l & 31)];
        *(short8*)(void*)&vfr[((((size_t)bh * 64 + kt) * 8 + chunk) * 64 + l) * 8] = o;
    }
}

// ---------------------------------------------------------------------------
// Flash attention — in-register P redistribution (v_permlane32_swap_b32,
// vdst[32:63]<->src0[0:31] semantics, proven R1/R2), RNE cvt_pk pack + f32
// VALU denominator (proven R3).
// This round: occupancy push. The two 32-key score blocks are processed
// SEQUENTIALLY (one f32x16 s-accumulator live at a time, -16 AGPR), and the
// V fragments are loaded in per-half groups of 4 next to their PV cluster
// (-16 VGPR live). Within-wave ILP drops, but at 4+ waves/SIMD cross-wave
// overlap covers it (the kernel was latency-bound at 2.4 waves/SIMD with
// MfmaUtil 31 + VALUBusy 48). s_setprio(1) wraps the MFMA clusters (T5).
// ---------------------------------------------------------------------------
__device__ inline void expack(
    const f32x16& s, f32x2& lp, bf16x8& pfa, bf16x8& pfb)
{
    float p0  = __builtin_amdgcn_exp2f(s[0]);
    float p1  = __builtin_amdgcn_exp2f(s[1]);
    float p2  = __builtin_amdgcn_exp2f(s[2]);
    float p3  = __builtin_amdgcn_exp2f(s[3]);
    float p4  = __builtin_amdgcn_exp2f(s[4]);
    float p5  = __builtin_amdgcn_exp2f(s[5]);
    float p6  = __builtin_amdgcn_exp2f(s[6]);
    float p7  = __builtin_amdgcn_exp2f(s[7]);
    float p8  = __builtin_amdgcn_exp2f(s[8]);
    float p9  = __builtin_amdgcn_exp2f(s[9]);
    float p10 = __builtin_amdgcn_exp2f(s[10]);
    float p11 = __builtin_amdgcn_exp2f(s[11]);
    float p12 = __builtin_amdgcn_exp2f(s[12]);
    float p13 = __builtin_amdgcn_exp2f(s[13]);
    float p14 = __builtin_amdgcn_exp2f(s[14]);
    float p15 = __builtin_amdgcn_exp2f(s[15]);

    lp += (f32x2){p0,  p1};
    lp += (f32x2){p2,  p3};
    lp += (f32x2){p4,  p5};
    lp += (f32x2){p6,  p7};
    lp += (f32x2){p8,  p9};
    lp += (f32x2){p10, p11};
    lp += (f32x2){p12, p13};
    lp += (f32x2){p14, p15};

    unsigned D0, D1, D2, D3, D4, D5, D6, D7;
    asm("v_cvt_pk_bf16_f32 %0, %1, %2" : "=v"(D0) : "v"(p0),  "v"(p1));
    asm("v_cvt_pk_bf16_f32 %0, %1, %2" : "=v"(D1) : "v"(p2),  "v"(p3));
    asm("v_cvt_pk_bf16_f32 %0, %1, %2" : "=v"(D2) : "v"(p4),  "v"(p5));
    asm("v_cvt_pk_bf16_f32 %0, %1, %2" : "=v"(D3) : "v"(p6),  "v"(p7));
    asm("v_cvt_pk_bf16_f32 %0, %1, %2" : "=v"(D4) : "v"(p8),  "v"(p9));
    asm("v_cvt_pk_bf16_f32 %0, %1, %2" : "=v"(D5) : "v"(p10), "v"(p11));
    asm("v_cvt_pk_bf16_f32 %0, %1, %2" : "=v"(D6) : "v"(p12), "v"(p13));
    asm("v_cvt_pk_bf16_f32 %0, %1, %2" : "=v"(D7) : "v"(p14), "v"(p15));
    // vdst_hi <-> src0_lo swaps: after these, (D0..D3) = frag ks=even,
    // (D4..D7) = frag ks=odd of this 32-key block.
    asm("v_permlane32_swap_b32 %0, %1" : "+v"(D0), "+v"(D2));
    asm("v_permlane32_swap_b32 %0, %1" : "+v"(D1), "+v"(D3));
    asm("v_permlane32_swap_b32 %0, %1" : "+v"(D4), "+v"(D6));
    asm("v_permlane32_swap_b32 %0, %1" : "+v"(D5), "+v"(D7));
    uint4v u0; u0[0] = D0; u0[1] = D1; u0[2] = D2; u0[3] = D3;
    uint4v u1; u1[0] = D4; u1[1] = D5; u1[2] = D6; u1[3] = D7;
    pfa = __builtin_bit_cast(bf16x8, u0);
    pfb = __builtin_bit_cast(bf16x8, u1);
}

__global__ __launch_bounds__(256, 4) void flash_ks(
    const short* __restrict__ qb, const short* __restrict__ kfr,
    const short* __restrict__ vfr, short* __restrict__ xbb)
{
    const int L = blockIdx.x;          // 0..1023
    const int xcd = L & 7;
    const int idx = L >> 3;            // 0..127
    const int bh = xcd * 2 + (idx & 1);
    const int qt = idx >> 1;           // 0..63: 64 q rows per block
    const int b = bh >> 3, h = bh & 7;
    const int w = threadIdx.x >> 6;
    const int qg = w >> 1;             // q-group 0/1 (32 rows each)
    const int kh = w & 1;              // key-half 0/1
    const int lane = threadIdx.x & 63;
    const int l31 = lane & 31;
    const int half = lane >> 5;

    // smem is ONLY the end-combine: redO [2][32][66] f32 + redl [4][32] f32
    __shared__ __align__(16) char smem[17408];

    const short* qrow = qb + (size_t)(b * 4096 + qt * 64 + qg * 32 + l31) * 256 + h * 32 + half * 8;
    bf16x8 qf0 = __builtin_bit_cast(bf16x8, *(const short8*)(const void*)qrow);
    bf16x8 qf1 = __builtin_bit_cast(bf16x8, *(const short8*)(const void*)(qrow + 16));

    f32x16 O0{}, O1{};
    f32x2 lp = (f32x2){0.f, 0.f};      // denominator pair-accumulator (f32)

    const short* kbase = kfr + ((size_t)bh * 64) * 4 * 512 + lane * 8;
    const short* vbase = vfr + ((size_t)bh * 64) * 8 * 512 + lane * 8;

#pragma unroll 1
    for (int t = 0; t < 32; ++t) {
        const int kt = kh * 32 + t;
        const short* kp = kbase + (size_t)kt * 4 * 512;
        const short* vp = vbase + (size_t)kt * 8 * 512;
        f32x16 zero{};

        // ---- half A: keys 0..31 of this 64-key tile (ks = 0,1) ----
        {
            bf16x8 k0 = __builtin_bit_cast(bf16x8, *(const short8*)(const void*)(kp + 0 * 512));
            bf16x8 k1 = __builtin_bit_cast(bf16x8, *(const short8*)(const void*)(kp + 1 * 512));
            __builtin_amdgcn_s_setprio(1);
            f32x16 s = __builtin_amdgcn_mfma_f32_32x32x16_bf16(k0, qf0, zero, 0, 0, 0);
            s = __builtin_amdgcn_mfma_f32_32x32x16_bf16(k1, qf1, s, 0, 0, 0);
            __builtin_amdgcn_s_setprio(0);
            bf16x8 v0 = __builtin_bit_cast(bf16x8, *(const short8*)(const void*)(vp + 0 * 512));
            bf16x8 v1 = __builtin_bit_cast(bf16x8, *(const short8*)(const void*)(vp + 1 * 512));
            bf16x8 v4 = __builtin_bit_cast(bf16x8, *(const short8*)(const void*)(vp + 4 * 512));
            bf16x8 v5 = __builtin_bit_cast(bf16x8, *(const short8*)(const void*)(vp + 5 * 512));
            bf16x8 pfa, pfb;
            expack(s, lp, pfa, pfb);
            __builtin_amdgcn_s_setprio(1);
            O0 = __builtin_amdgcn_mfma_f32_32x32x16_bf16(pfa, v0, O0, 0, 0, 0);
            O0 = __builtin_amdgcn_mfma_f32_32x32x16_bf16(pfb, v1, O0, 0, 0, 0);
            O1 = __builtin_amdgcn_mfma_f32_32x32x16_bf16(pfa, v4, O1, 0, 0, 0);
            O1 = __builtin_amdgcn_mfma_f32_32x32x16_bf16(pfb, v5, O1, 0, 0, 0);
            __builtin_amdgcn_s_setprio(0);
        }
        // ---- half B: keys 32..63 (ks = 2,3) ----
        {
            bf16x8 k2 = __builtin_bit_cast(bf16x8, *(const short8*)(const void*)(kp + 2 * 512));
            bf16x8 k3 = __builtin_bit_cast(bf16x8, *(const short8*)(const void*)(kp + 3 * 512));
            __builtin_amdgcn_s_setprio(1);
            f32x16 s = __builtin_amdgcn_mfma_f32_32x32x16_bf16(k2, qf0, zero, 0, 0, 0);
            s = __builtin_amdgcn_mfma_f32_32x32x16_bf16(k3, qf1, s, 0, 0, 0);
            __builtin_amdgcn_s_setprio(0);
            bf16x8 v2 = __builtin_bit_cast(bf16x8, *(const short8*)(const void*)(vp + 2 * 512));
            bf16x8 v3 = __builtin_bit_cast(bf16x8, *(const short8*)(const void*)(vp + 3 * 512));
            bf16x8 v6 = __builtin_bit_cast(bf16x8, *(const short8*)(const void*)(vp + 6 * 512));
            bf16x8 v7 = __builtin_bit_cast(bf16x8, *(const short8*)(const void*)(vp + 7 * 512));
            bf16x8 pfa, pfb;
            expack(s, lp, pfa, pfb);
            __builtin_amdgcn_s_setprio(1);
            O0 = __builtin_amdgcn_mfma_f32_32x32x16_bf16(pfa, v2, O0, 0, 0, 0);
            O0 = __builtin_amdgcn_mfma_f32_32x32x16_bf16(pfb, v3, O0, 0, 0, 0);
            O1 = __builtin_amdgcn_mfma_f32_32x32x16_bf16(pfa, v6, O1, 0, 0, 0);
            O1 = __builtin_amdgcn_mfma_f32_32x32x16_bf16(pfb, v7, O1, 0, 0, 0);
            __builtin_amdgcn_s_setprio(0);
        }
    }

    // denominator: combine pair-accumulator, then lane halves (h0 + h1).
    float lsum = lp[0] + lp[1];
    float lother = lsum;
    asm("v_permlane32_swap_b32 %0, %1" : "+v"(lsum), "+v"(lother));
    lsum += lother;                    // full per-(qg,kh) sum, every lane

    // ---- combine key-half pairs per q-group ----
    float* redO = (float*)smem;              // [qg][32 q][66] = 16896 B
    float* redl = (float*)(smem + 16896);    // [qg*2+kh][32 q] = 512 B
    if (half == 0)
        redl[(qg * 2 + kh) * 32 + l31] = lsum;
    if (kh == 1) {
        float* Bo = redO + qg * 32 * 66;
#pragma unroll
        for (int r = 0; r < 16; ++r) {
            int q = (r & 3) + 8 * (r >> 2) + 4 * half;
            Bo[q * 66 + l31] = O0[r];
            Bo[q * 66 + 32 + l31] = O1[r];
        }
    }
    __syncthreads();
    if (kh == 0) {
        const float* Bo = redO + qg * 32 * 66;
#pragma unroll
        for (int r = 0; r < 16; ++r) {
            int q = (r & 3) + 8 * (r >> 2) + 4 * half;
            float o0 = O0[r] + Bo[q * 66 + l31];
            float o1 = O1[r] + Bo[q * 66 + 32 + l31];
            float inv = 1.f / (redl[(qg * 2 + 0) * 32 + q] + redl[(qg * 2 + 1) * 32 + q]);
            size_t row = (size_t)(b * 4096 + qt * 64 + qg * 32 + q);
            short* d = xbb + row * 512 + h * 64 + l31;
            d[0] = f2bf(o0 * inv);
            d[32] = f2bf(o1 * inv);
        }
    }
}

// ---------------------------------------------------------------------------
extern "C" void kernel_launch(void* const* d_in, const int* in_sizes, int n_in,
                              void* d_out, int out_size, void* d_ws, size_t ws_size,
                              hipStream_t stream)
{
    const float* query = (const float*)d_in[0];
    const float* key   = (const float*)d_in[1];
    const float* value = (const float*)d_in[2];
    const float* Wq1   = (const float*)d_in[3];
    const float* bq1   = (const float*)d_in[4];
    const float* Wq2   = (const float*)d_in[5];
    const float* bq2   = (const float*)d_in[6];
    const float* Wk1   = (const float*)d_in[7];
    const float* bk1   = (const float*)d_in[8];
    const float* Wk2   = (const float*)d_in[9];
    const float* bk2   = (const float*)d_in[10];
    const float* Wv    = (const float*)d_in[11];
    const float* bv    = (const float*)d_in[12];
    const float* Wo    = (const float*)d_in[13];
    const float* bo    = (const float*)d_in[14];
    float* out = (float*)d_out;

    // Workspace (bytes), overlays (proven R13):
    char* ws = (char*)d_ws;
    short* H1q   = (short*)(ws + 0);
    short* H1k   = (short*)(ws + 16777216);
    short* xbb   = (short*)(ws + 0);
    short* qcast = (short*)(ws + 33554432);
    short* kcast = (short*)(ws + 41943040);
    short* vcast = (short*)(ws + 50331648);
    short* qbb   = (short*)(ws + 33554432);
    short* kbb   = (short*)(ws + 37748736);
    short* vbb   = (short*)(ws + 41943040);
    short* kfr   = (short*)(ws + 50331648);
    short* vfr   = (short*)(ws + 54525952);
    short* Wq1t  = (short*)(ws + 62914560);
    short* Wk1t  = (short*)(ws + 63963136);
    short* Wq2t  = (short*)(ws + 65011712);
    short* Wk2t  = (short*)(ws + 65536000);
    short* Wvt   = (short*)(ws + 66060288);
    short* Wot   = (short*)(ws + 66584576);   // 512 KB -> end 67,108,864

    dim3 blk(256);
    const float qscale = 0.17677669529663687f * 1.4426950408889634f;

    // fused input casts + weight prep (one dispatch)
    prep_all<<<dim3(8192), blk, 0, stream>>>(
        query, key, value, qcast, kcast, vcast,
        Wq1, Wk1, Wq2, Wk2, Wv, Wo, Wq1t, Wk1t, Wq2t, Wk2t, Wvt, Wot);

    // MLP layer 1 (q & k batched): GELU, bf16. N=1024, K=512, BM=128, BN=128
    gemm_bt<1, 0, 128, 128><<<dim3(8 * 64, 1, 2), blk, 0, stream>>>(
        qcast, kcast, Wq1t, Wk1t, bq1, bk1, H1q, H1k, 1.f, 1.f, 8, 1024, 512);
    // MLP layer 2 (q & k batched): q pre-scaled. N=256, K=1024, BM=64, BN=64
    gemm_bt<0, 0, 64, 64><<<dim3(4 * 128, 1, 2), blk, 0, stream>>>(
        H1q, H1k, Wq2t, Wk2t, bq2, bk2, qbb, kbb, qscale, 1.f, 4, 256, 1024);
    // v projection: N=512, K=512, BM=64, BN=64
    gemm_bt<0, 0, 64, 64><<<dim3(8 * 128, 1, 1), blk, 0, stream>>>(
        vcast, vcast, Wvt, Wvt, bv, bv, vbb, vbb, 1.f, 1.f, 8, 512, 512);
    // fused frag-major repacks (one dispatch)
    repack_kv<<<dim3(64, 32), blk, 0, stream>>>(kbb, kfr, vbb, vfr);
    // attention: flash with in-register P redistribution, VALU denominator
    flash_ks<<<dim3(1024), blk, 0, stream>>>(qbb, kfr, vfr, xbb);
    // output projection: N=512, K=512, BM=64, BN=64 -> f32
    gemm_bt<0, 1, 64, 64><<<dim3(8 * 128, 1, 1), blk, 0, stream>>>(
        xbb, xbb, Wot, Wot, bo, bo, out, out, 1.f, 1.f, 8, 512, 512);
}

// Round 5
// 259.962 us; speedup vs baseline: 1.0201x; 1.0201x over previous
//
#include <hip/hip_runtime.h>
#include <math.h>

typedef __attribute__((ext_vector_type(8))) short short8;
typedef __bf16 bf16x8 __attribute__((ext_vector_type(8)));
typedef __attribute__((ext_vector_type(4))) float f32x4;
typedef __attribute__((ext_vector_type(2))) float f32x2;
typedef __attribute__((ext_vector_type(16))) float f32x16;
typedef __attribute__((ext_vector_type(4))) unsigned uint4v;

__device__ inline short f2bf(float f) {
    unsigned u = __builtin_bit_cast(unsigned, f);
    u += 0x7fff + ((u >> 16) & 1);   // round-to-nearest-even
    return (short)(u >> 16);
}
__device__ inline float bf2f(short h) {
    return __builtin_bit_cast(float, ((unsigned)(unsigned short)h) << 16);
}
__device__ inline float gelu_f(float x) {
    return 0.5f * x * (1.f + erff(x * 0.70710678118654752f));
}

// global->LDS direct DMA, 16B per lane. Dest is wave-uniform base; HW writes
// base + lane*16. Source address is per-lane (pre-swizzled for XOR layout).
__device__ inline void gload_lds16(const void* g, void* l) {
    __builtin_amdgcn_global_load_lds(
        (const __attribute__((address_space(1))) unsigned int*)g,
        (__attribute__((address_space(3))) unsigned int*)l, 16, 0, 0);
}

// ---------------------------------------------------------------------------
// Fused prep: input casts (blocks 0..6143) + all 6 weight transposes
// (blocks 6144..8191, all plain bf16 [N][K]). Block-uniform branches.
// ---------------------------------------------------------------------------
__global__ __launch_bounds__(256) void prep_all(
    const float* __restrict__ q, const float* __restrict__ k,
    const float* __restrict__ v,
    short* __restrict__ qc, short* __restrict__ kc, short* __restrict__ vc,
    const float* __restrict__ Wq1, const float* __restrict__ Wk1,
    const float* __restrict__ Wq2, const float* __restrict__ Wk2,
    const float* __restrict__ Wv,  const float* __restrict__ Wo,
    short* __restrict__ Wq1t, short* __restrict__ Wk1t,
    short* __restrict__ Wq2t, short* __restrict__ Wk2t,
    short* __restrict__ Wvt,  short* __restrict__ Wot)
{
    int id = blockIdx.x;
    if (id < 6144) {
        const float* src = id < 2048 ? q : (id < 4096 ? k : v);
        short* dst = id < 2048 ? qc : (id < 4096 ? kc : vc);
        int blk = id & 2047;
        size_t i = ((size_t)blk * 256 + threadIdx.x) * 8;
        float4 a = *(const float4*)(src + i);
        float4 b = *(const float4*)(src + i + 4);
        short8 o;
        o[0] = f2bf(a.x); o[1] = f2bf(a.y); o[2] = f2bf(a.z); o[3] = f2bf(a.w);
        o[4] = f2bf(b.x); o[5] = f2bf(b.y); o[6] = f2bf(b.z); o[7] = f2bf(b.w);
        *(short8*)(void*)(dst + i) = o;
        return;
    }
    id -= 6144;
    const float* W; short* Wt; int K, N;
    if (id < 512)       { W = Wq1; Wt = Wq1t; K = 512;  N = 1024; }
    else if (id < 1024) { W = Wk1; Wt = Wk1t; K = 512;  N = 1024; id -= 512; }
    else if (id < 1280) { W = Wq2; Wt = Wq2t; K = 1024; N = 256;  id -= 1024; }
    else if (id < 1536) { W = Wk2; Wt = Wk2t; K = 1024; N = 256;  id -= 1280; }
    else if (id < 1792) { W = Wv;  Wt = Wvt;  K = 512;  N = 512;  id -= 1536; }
    else                { W = Wo;  Wt = Wot;  K = 512;  N = 512;  id -= 1792; }
    int nx = N >> 5;
    int n0 = (id % nx) * 32, k0 = (id / nx) * 32;

    __shared__ float T[32][33];
    int tid = threadIdx.x;
    int r = tid >> 3, c4 = (tid & 7) * 4;
    float4 v4 = *(const float4*)&W[(size_t)(k0 + r) * N + n0 + c4];
    T[r][c4 + 0] = v4.x; T[r][c4 + 1] = v4.y; T[r][c4 + 2] = v4.z; T[r][c4 + 3] = v4.w;
    __syncthreads();
    short4 o;
    o.x = f2bf(T[c4 + 0][r]);
    o.y = f2bf(T[c4 + 1][r]);
    o.z = f2bf(T[c4 + 2][r]);
    o.w = f2bf(T[c4 + 3][r]);
    *(short4*)&Wt[(size_t)(n0 + r) * K + k0 + c4] = o;
}

// ---------------------------------------------------------------------------
// bf16 MFMA GEMM, B^T layout, BK=64, XCD-aware swizzle. BM/BN templated.
// This round: staging switched from reg-staging (global->reg->ds_write) to
// global_load_lds width=16 with PRE-SWIZZLED SOURCE (m151: 646->874 TF at
// 128²; m173 both-sides-or-neither rule). The XOR permutes 16B chunks within
// one 128B cache line, so coalescing is unchanged; LDS dest is linear
// lane-contiguous; read-side addressing is byte-identical to before.
// ---------------------------------------------------------------------------
template <int ACT, int OUTF32, int BM, int BN>
__global__ __launch_bounds__(256) void gemm_bt(
    const short* __restrict__ A0, const short* __restrict__ A1,
    const short* __restrict__ B0, const short* __restrict__ B1,
    const float* __restrict__ b0, const float* __restrict__ b1,
    void* C0_, void* C1_,
    float s0, float s1, int nbn, int N, int K)
{
    constexpr int MT = BM / 32;        // m-tiles per wave
    constexpr int NT = BN / 32;        // n-tiles per wave
    const int z = blockIdx.z;
    const short* A = z ? A1 : A0;
    const short* B = z ? B1 : B0;
    const float* bias = z ? b1 : b0;
    void* C_ = z ? C1_ : C0_;
    const float scale = z ? s1 : s0;

    const int L = blockIdx.x;
    const int xcd = L & 7;
    const int per = L >> 3;
    const int bn = (per % nbn) * BN;
    const int bm = ((per / nbn) * 8 + xcd) * BM;

    const int tid = threadIdx.x;
    const int w = tid >> 6;
    const int lane = tid & 63;
    const int l15 = lane & 15, quad = lane >> 4;
    const int wm = (w >> 1) * (BM / 2), wn = (w & 1) * (BN / 2);

    __shared__ __align__(16) short As[BM * 64];
    __shared__ __align__(16) short Bs[BN * 64];

    f32x4 acc[MT][NT];
#pragma unroll
    for (int mt = 0; mt < MT; ++mt)
#pragma unroll
        for (int nt = 0; nt < NT; ++nt) acc[mt][nt] = (f32x4){0.f, 0.f, 0.f, 0.f};

    for (int k0 = 0; k0 < K; k0 += 64) {
#pragma unroll
        for (int i = 0; i < BM / 32; ++i) {
            int ga = tid + i * 256;
            int row = ga >> 3, g = ga & 7;
            gload_lds16(&A[(size_t)(bm + row) * K + k0 + ((g ^ (row & 7)) * 8)],
                        &As[(i * 256 + w * 64) * 8]);
        }
#pragma unroll
        for (int i = 0; i < BN / 32; ++i) {
            int gb = tid + i * 256;
            int row = gb >> 3, g = gb & 7;
            gload_lds16(&B[(size_t)(bn + row) * K + k0 + ((g ^ (row & 7)) * 8)],
                        &Bs[(i * 256 + w * 64) * 8]);
        }
        __syncthreads();

#pragma unroll
        for (int ks = 0; ks < 2; ++ks) {
            bf16x8 af[MT], bfr[NT];
#pragma unroll
            for (int t = 0; t < MT; ++t) {
                int row = wm + t * 16 + l15;
                af[t] = __builtin_bit_cast(bf16x8,
                    *(const short8*)(const void*)&As[row * 64 + (((ks * 4 + quad) ^ (row & 7)) * 8)]);
            }
#pragma unroll
            for (int t = 0; t < NT; ++t) {
                int row = wn + t * 16 + l15;
                bfr[t] = __builtin_bit_cast(bf16x8,
                    *(const short8*)(const void*)&Bs[row * 64 + (((ks * 4 + quad) ^ (row & 7)) * 8)]);
            }
#pragma unroll
            for (int mt = 0; mt < MT; ++mt)
#pragma unroll
                for (int nt = 0; nt < NT; ++nt)
                    acc[mt][nt] = __builtin_amdgcn_mfma_f32_16x16x32_bf16(af[mt], bfr[nt], acc[mt][nt], 0, 0, 0);
        }
        __syncthreads();
    }

    float bv[NT];
#pragma unroll
    for (int nt = 0; nt < NT; ++nt) bv[nt] = bias[bn + wn + nt * 16 + l15];
#pragma unroll
    for (int mt = 0; mt < MT; ++mt)
#pragma unroll
        for (int r = 0; r < 4; ++r) {
            int row = bm + wm + mt * 16 + quad * 4 + r;
#pragma unroll
            for (int nt = 0; nt < NT; ++nt) {
                float v = acc[mt][nt][r] + bv[nt];
                if (ACT) v = gelu_f(v);
                v *= scale;
                int col = bn + wn + nt * 16 + l15;
                if (OUTF32) ((float*)C_)[(size_t)row * N + col] = v;
                else        ((short*)C_)[(size_t)row * N + col] = f2bf(v);
            }
        }
}

// ---------------------------------------------------------------------------
// Fused K+V repack (proven R14). y < 16: K-repack; y >= 16: V-repack.
// ---------------------------------------------------------------------------
__global__ __launch_bounds__(256) void repack_kv(
    const short* __restrict__ kb, short* __restrict__ kfr,
    const short* __restrict__ vbb, short* __restrict__ vfr)
{
    const int kt = blockIdx.x;
    const int y = blockIdx.y;
    const int t = threadIdx.x;
    __shared__ short Vt[64][72];   // [key][dk] (V path only)

    if (y < 16) {
        const int bh = y;
        const int b = bh >> 3, h = bh & 7;
        const int c = t >> 6, l = t & 63;
        const int nt = c >> 1, ks = c & 1;
        int key = kt * 64 + nt * 32 + (l & 31);
        int k = ks * 16 + (l >> 5) * 8;
        short8 v = *(const short8*)(const void*)&kb[(size_t)(b * 4096 + key) * 256 + h * 32 + k];
        *(short8*)(void*)&kfr[((((size_t)bh * 64 + kt) * 4 + c) * 64 + l) * 8] = v;
        return;
    }
    const int bh = y - 16;
    const int b = bh >> 3, h = bh & 7;
#pragma unroll
    for (int it = 0; it < 2; ++it) {
        int idx = t + it * 256;
        int keyr = idx >> 3, c8 = (idx & 7) * 8;
        *(short8*)(void*)&Vt[keyr][c8] =
            *(const short8*)(const void*)&vbb[(size_t)(b * 4096 + kt * 64 + keyr) * 512 + h * 64 + c8];
    }
    __syncthreads();
#pragma unroll
    for (int it = 0; it < 2; ++it) {
        int chunk = (t >> 6) * 2 + it;
        int l = t & 63;
        int dt = chunk >> 2, ks = chunk & 3;
        short8 o;
#pragma unroll
        for (int j = 0; j < 8; ++j)
            o[j] = Vt[ks * 16 + (l >> 5) * 8 + j][dt * 32 + (l & 31)];
        *(short8*)(void*)&vfr[((((size_t)bh * 64 + kt) * 8 + chunk) * 64 + l) * 8] = o;
    }
}

// ---------------------------------------------------------------------------
// Flash attention — R3 proven form, verbatim (70.0 µs, VGPR 64, occ 30%).
// In-register P redistribution (v_permlane32_swap_b32, vdst[32:63]<->
// src0[0:31]), RNE cvt_pk pack, f32 VALU denominator. R4's sequential-halves
// + setprio variant regressed (77.5 µs: ILP loss > occupancy gain) — reverted.
// ---------------------------------------------------------------------------
__global__ __launch_bounds__(256, 4) void flash_ks(
    const short* __restrict__ qb, const short* __restrict__ kfr,
    const short* __restrict__ vfr, short* __restrict__ xbb)
{
    const int L = blockIdx.x;          // 0..1023
    const int xcd = L & 7;
    const int idx = L >> 3;            // 0..127
    const int bh = xcd * 2 + (idx & 1);
    const int qt = idx >> 1;           // 0..63: 64 q rows per block
    const int b = bh >> 3, h = bh & 7;
    const int w = threadIdx.x >> 6;
    const int qg = w >> 1;             // q-group 0/1 (32 rows each)
    const int kh = w & 1;              // key-half 0/1
    const int lane = threadIdx.x & 63;
    const int l31 = lane & 31;
    const int half = lane >> 5;

    // smem is ONLY the end-combine: redO [2][32][66] f32 + redl [4][32] f32
    __shared__ __align__(16) char smem[17408];

    const short* qrow = qb + (size_t)(b * 4096 + qt * 64 + qg * 32 + l31) * 256 + h * 32 + half * 8;
    bf16x8 qf0 = __builtin_bit_cast(bf16x8, *(const short8*)(const void*)qrow);
    bf16x8 qf1 = __builtin_bit_cast(bf16x8, *(const short8*)(const void*)(qrow + 16));

    f32x16 O0{}, O1{};
    f32x2 lp = (f32x2){0.f, 0.f};      // denominator pair-accumulator (f32)

    const short* kbase = kfr + ((size_t)bh * 64) * 4 * 512 + lane * 8;
    const short* vbase = vfr + ((size_t)bh * 64) * 8 * 512 + lane * 8;

#pragma unroll 1
    for (int t = 0; t < 32; ++t) {
        const int kt = kh * 32 + t;
        bf16x8 kc[4], vc[8];
        const short* kp = kbase + (size_t)kt * 4 * 512;
        const short* vp = vbase + (size_t)kt * 8 * 512;
#pragma unroll
        for (int c = 0; c < 4; ++c)
            kc[c] = __builtin_bit_cast(bf16x8, *(const short8*)(const void*)(kp + c * 512));
#pragma unroll
        for (int c = 0; c < 8; ++c)
            vc[c] = __builtin_bit_cast(bf16x8, *(const short8*)(const void*)(vp + c * 512));

        f32x16 zero{};
        f32x16 s0 = __builtin_amdgcn_mfma_f32_32x32x16_bf16(kc[0], qf0, zero, 0, 0, 0);
        s0 = __builtin_amdgcn_mfma_f32_32x32x16_bf16(kc[1], qf1, s0, 0, 0, 0);
        f32x16 s1 = __builtin_amdgcn_mfma_f32_32x32x16_bf16(kc[2], qf0, zero, 0, 0, 0);
        s1 = __builtin_amdgcn_mfma_f32_32x32x16_bf16(kc[3], qf1, s1, 0, 0, 0);

        // exp + RNE cvt_pk pack + in-register cross-half redistribution;
        // denominator accumulated as f32 pair-sums (consistent w/ RNE pack).
        bf16x8 pf[4];
#pragma unroll
        for (int nt = 0; nt < 2; ++nt) {
            const f32x16& s = nt ? s1 : s0;
            float p0  = __builtin_amdgcn_exp2f(s[0]);
            float p1  = __builtin_amdgcn_exp2f(s[1]);
            float p2  = __builtin_amdgcn_exp2f(s[2]);
            float p3  = __builtin_amdgcn_exp2f(s[3]);
            float p4  = __builtin_amdgcn_exp2f(s[4]);
            float p5  = __builtin_amdgcn_exp2f(s[5]);
            float p6  = __builtin_amdgcn_exp2f(s[6]);
            float p7  = __builtin_amdgcn_exp2f(s[7]);
            float p8  = __builtin_amdgcn_exp2f(s[8]);
            float p9  = __builtin_amdgcn_exp2f(s[9]);
            float p10 = __builtin_amdgcn_exp2f(s[10]);
            float p11 = __builtin_amdgcn_exp2f(s[11]);
            float p12 = __builtin_amdgcn_exp2f(s[12]);
            float p13 = __builtin_amdgcn_exp2f(s[13]);
            float p14 = __builtin_amdgcn_exp2f(s[14]);
            float p15 = __builtin_amdgcn_exp2f(s[15]);

            lp += (f32x2){p0,  p1};
            lp += (f32x2){p2,  p3};
            lp += (f32x2){p4,  p5};
            lp += (f32x2){p6,  p7};
            lp += (f32x2){p8,  p9};
            lp += (f32x2){p10, p11};
            lp += (f32x2){p12, p13};
            lp += (f32x2){p14, p15};

            unsigned D0, D1, D2, D3, D4, D5, D6, D7;
            asm("v_cvt_pk_bf16_f32 %0, %1, %2" : "=v"(D0) : "v"(p0),  "v"(p1));
            asm("v_cvt_pk_bf16_f32 %0, %1, %2" : "=v"(D1) : "v"(p2),  "v"(p3));
            asm("v_cvt_pk_bf16_f32 %0, %1, %2" : "=v"(D2) : "v"(p4),  "v"(p5));
            asm("v_cvt_pk_bf16_f32 %0, %1, %2" : "=v"(D3) : "v"(p6),  "v"(p7));
            asm("v_cvt_pk_bf16_f32 %0, %1, %2" : "=v"(D4) : "v"(p8),  "v"(p9));
            asm("v_cvt_pk_bf16_f32 %0, %1, %2" : "=v"(D5) : "v"(p10), "v"(p11));
            asm("v_cvt_pk_bf16_f32 %0, %1, %2" : "=v"(D6) : "v"(p12), "v"(p13));
            asm("v_cvt_pk_bf16_f32 %0, %1, %2" : "=v"(D7) : "v"(p14), "v"(p15));
            // vdst_hi <-> src0_lo swaps: after these, (D0,D1,D2,D3) are the
            // 4 dwords of frag ks=2nt, (D4,D5,D6,D7) the dwords of ks=2nt+1.
            asm("v_permlane32_swap_b32 %0, %1" : "+v"(D0), "+v"(D2));
            asm("v_permlane32_swap_b32 %0, %1" : "+v"(D1), "+v"(D3));
            asm("v_permlane32_swap_b32 %0, %1" : "+v"(D4), "+v"(D6));
            asm("v_permlane32_swap_b32 %0, %1" : "+v"(D5), "+v"(D7));
            uint4v u0; u0[0] = D0; u0[1] = D1; u0[2] = D2; u0[3] = D3;
            uint4v u1; u1[0] = D4; u1[1] = D5; u1[2] = D6; u1[3] = D7;
            pf[2 * nt + 0] = __builtin_bit_cast(bf16x8, u0);
            pf[2 * nt + 1] = __builtin_bit_cast(bf16x8, u1);
        }

#pragma unroll
        for (int ks = 0; ks < 4; ++ks) {
            O0 = __builtin_amdgcn_mfma_f32_32x32x16_bf16(pf[ks], vc[ks], O0, 0, 0, 0);
            O1 = __builtin_amdgcn_mfma_f32_32x32x16_bf16(pf[ks], vc[4 + ks], O1, 0, 0, 0);
        }
    }

    // denominator: combine pair-accumulator, then lane halves (h0 + h1).
    float lsum = lp[0] + lp[1];
    float lother = lsum;
    asm("v_permlane32_swap_b32 %0, %1" : "+v"(lsum), "+v"(lother));
    lsum += lother;                    // full per-(qg,kh) sum, every lane

    // ---- combine key-half pairs per q-group ----
    float* redO = (float*)smem;              // [qg][32 q][66] = 16896 B
    float* redl = (float*)(smem + 16896);    // [qg*2+kh][32 q] = 512 B
    if (half == 0)
        redl[(qg * 2 + kh) * 32 + l31] = lsum;
    if (kh == 1) {
        float* Bo = redO + qg * 32 * 66;
#pragma unroll
        for (int r = 0; r < 16; ++r) {
            int q = (r & 3) + 8 * (r >> 2) + 4 * half;
            Bo[q * 66 + l31] = O0[r];
            Bo[q * 66 + 32 + l31] = O1[r];
        }
    }
    __syncthreads();
    if (kh == 0) {
        const float* Bo = redO + qg * 32 * 66;
#pragma unroll
        for (int r = 0; r < 16; ++r) {
            int q = (r & 3) + 8 * (r >> 2) + 4 * half;
            float o0 = O0[r] + Bo[q * 66 + l31];
            float o1 = O1[r] + Bo[q * 66 + 32 + l31];
            float inv = 1.f / (redl[(qg * 2 + 0) * 32 + q] + redl[(qg * 2 + 1) * 32 + q]);
            size_t row = (size_t)(b * 4096 + qt * 64 + qg * 32 + q);
            short* d = xbb + row * 512 + h * 64 + l31;
            d[0] = f2bf(o0 * inv);
            d[32] = f2bf(o1 * inv);
        }
    }
}

// ---------------------------------------------------------------------------
extern "C" void kernel_launch(void* const* d_in, const int* in_sizes, int n_in,
                              void* d_out, int out_size, void* d_ws, size_t ws_size,
                              hipStream_t stream)
{
    const float* query = (const float*)d_in[0];
    const float* key   = (const float*)d_in[1];
    const float* value = (const float*)d_in[2];
    const float* Wq1   = (const float*)d_in[3];
    const float* bq1   = (const float*)d_in[4];
    const float* Wq2   = (const float*)d_in[5];
    const float* bq2   = (const float*)d_in[6];
    const float* Wk1   = (const float*)d_in[7];
    const float* bk1   = (const float*)d_in[8];
    const float* Wk2   = (const float*)d_in[9];
    const float* bk2   = (const float*)d_in[10];
    const float* Wv    = (const float*)d_in[11];
    const float* bv    = (const float*)d_in[12];
    const float* Wo    = (const float*)d_in[13];
    const float* bo    = (const float*)d_in[14];
    float* out = (float*)d_out;

    // Workspace (bytes), overlays (proven R13):
    char* ws = (char*)d_ws;
    short* H1q   = (short*)(ws + 0);
    short* H1k   = (short*)(ws + 16777216);
    short* xbb   = (short*)(ws + 0);
    short* qcast = (short*)(ws + 33554432);
    short* kcast = (short*)(ws + 41943040);
    short* vcast = (short*)(ws + 50331648);
    short* qbb   = (short*)(ws + 33554432);
    short* kbb   = (short*)(ws + 37748736);
    short* vbb   = (short*)(ws + 41943040);
    short* kfr   = (short*)(ws + 50331648);
    short* vfr   = (short*)(ws + 54525952);
    short* Wq1t  = (short*)(ws + 62914560);
    short* Wk1t  = (short*)(ws + 63963136);
    short* Wq2t  = (short*)(ws + 65011712);
    short* Wk2t  = (short*)(ws + 65536000);
    short* Wvt   = (short*)(ws + 66060288);
    short* Wot   = (short*)(ws + 66584576);   // 512 KB -> end 67,108,864

    dim3 blk(256);
    const float qscale = 0.17677669529663687f * 1.4426950408889634f;

    // fused input casts + weight prep (one dispatch)
    prep_all<<<dim3(8192), blk, 0, stream>>>(
        query, key, value, qcast, kcast, vcast,
        Wq1, Wk1, Wq2, Wk2, Wv, Wo, Wq1t, Wk1t, Wq2t, Wk2t, Wvt, Wot);

    // MLP layer 1 (q & k batched): GELU, bf16. N=1024, K=512, BM=128, BN=128
    gemm_bt<1, 0, 128, 128><<<dim3(8 * 64, 1, 2), blk, 0, stream>>>(
        qcast, kcast, Wq1t, Wk1t, bq1, bk1, H1q, H1k, 1.f, 1.f, 8, 1024, 512);
    // MLP layer 2 (q & k batched): q pre-scaled. N=256, K=1024, BM=64, BN=64
    gemm_bt<0, 0, 64, 64><<<dim3(4 * 128, 1, 2), blk, 0, stream>>>(
        H1q, H1k, Wq2t, Wk2t, bq2, bk2, qbb, kbb, qscale, 1.f, 4, 256, 1024);
    // v projection: N=512, K=512, BM=64, BN=64
    gemm_bt<0, 0, 64, 64><<<dim3(8 * 128, 1, 1), blk, 0, stream>>>(
        vcast, vcast, Wvt, Wvt, bv, bv, vbb, vbb, 1.f, 1.f, 8, 512, 512);
    // fused frag-major repacks (one dispatch)
    repack_kv<<<dim3(64, 32), blk, 0, stream>>>(kbb, kfr, vbb, vfr);
    // attention: flash with in-register P redistribution, VALU denominator
    flash_ks<<<dim3(1024), blk, 0, stream>>>(qbb, kfr, vfr, xbb);
    // output projection: N=512, K=512, BM=64, BN=64 -> f32
    gemm_bt<0, 1, 64, 64><<<dim3(8 * 128, 1, 1), blk, 0, stream>>>(
        xbb, xbb, Wot, Wot, bo, bo, out, out, 1.f, 1.f, 8, 512, 512);
}

// Round 6
// 259.364 us; speedup vs baseline: 1.0224x; 1.0023x over previous
//
#include <hip/hip_runtime.h>
#include <math.h>

typedef __attribute__((ext_vector_type(8))) short short8;
typedef __bf16 bf16x8 __attribute__((ext_vector_type(8)));
typedef __attribute__((ext_vector_type(4))) float f32x4;
typedef __attribute__((ext_vector_type(2))) float f32x2;
typedef __attribute__((ext_vector_type(16))) float f32x16;
typedef __attribute__((ext_vector_type(4))) unsigned uint4v;

__device__ inline short f2bf(float f) {
    unsigned u = __builtin_bit_cast(unsigned, f);
    u += 0x7fff + ((u >> 16) & 1);   // round-to-nearest-even
    return (short)(u >> 16);
}
__device__ inline float gelu_f(float x) {
    return 0.5f * x * (1.f + erff(x * 0.70710678118654752f));
}

// global->LDS direct DMA, 16B per lane. Dest is wave-uniform base; HW writes
// base + lane*16. Source address is per-lane (pre-swizzled for XOR layout).
__device__ inline void gload_lds16(const void* g, void* l) {
    __builtin_amdgcn_global_load_lds(
        (const __attribute__((address_space(1))) unsigned int*)g,
        (__attribute__((address_space(3))) unsigned int*)l, 16, 0, 0);
}

// ---------------------------------------------------------------------------
// Weight prep only (input casts are now fused into the GEMM A-staging).
// 2048 blocks, all 6 weight transposes to bf16 [N][K].
// ---------------------------------------------------------------------------
__global__ __launch_bounds__(256) void prep_w(
    const float* __restrict__ Wq1, const float* __restrict__ Wk1,
    const float* __restrict__ Wq2, const float* __restrict__ Wk2,
    const float* __restrict__ Wv,  const float* __restrict__ Wo,
    short* __restrict__ Wq1t, short* __restrict__ Wk1t,
    short* __restrict__ Wq2t, short* __restrict__ Wk2t,
    short* __restrict__ Wvt,  short* __restrict__ Wot)
{
    int id = blockIdx.x;
    const float* W; short* Wt; int K, N;
    if (id < 512)       { W = Wq1; Wt = Wq1t; K = 512;  N = 1024; }
    else if (id < 1024) { W = Wk1; Wt = Wk1t; K = 512;  N = 1024; id -= 512; }
    else if (id < 1280) { W = Wq2; Wt = Wq2t; K = 1024; N = 256;  id -= 1024; }
    else if (id < 1536) { W = Wk2; Wt = Wk2t; K = 1024; N = 256;  id -= 1280; }
    else if (id < 1792) { W = Wv;  Wt = Wvt;  K = 512;  N = 512;  id -= 1536; }
    else                { W = Wo;  Wt = Wot;  K = 512;  N = 512;  id -= 1792; }
    int nx = N >> 5;
    int n0 = (id % nx) * 32, k0 = (id / nx) * 32;

    __shared__ float T[32][33];
    int tid = threadIdx.x;
    int r = tid >> 3, c4 = (tid & 7) * 4;
    float4 v4 = *(const float4*)&W[(size_t)(k0 + r) * N + n0 + c4];
    T[r][c4 + 0] = v4.x; T[r][c4 + 1] = v4.y; T[r][c4 + 2] = v4.z; T[r][c4 + 3] = v4.w;
    __syncthreads();
    short4 o;
    o.x = f2bf(T[c4 + 0][r]);
    o.y = f2bf(T[c4 + 1][r]);
    o.z = f2bf(T[c4 + 2][r]);
    o.w = f2bf(T[c4 + 3][r]);
    *(short4*)&Wt[(size_t)(n0 + r) * K + k0 + c4] = o;
}

// ---------------------------------------------------------------------------
// bf16 MFMA GEMM, B^T layout, BK=64, XCD-aware swizzle. BM/BN templated.
// AF32: A is raw f32 — reg-stage f32 -> v_cvt_pk_bf16_f32 (RNE) -> ds_write
//       (fuses the former input-cast pass into the GEMM).
// OM (output mode, per z): 0 = bf16 plain [row][col], 1 = f32 plain,
//       2 = kfr frag-major scatter (fuses the former K-repack),
//       3 = vfr frag-major scatter (fuses the former V-repack).
// Scatter mappings are the exact inverse of repack_kv's forward mapping.
// ---------------------------------------------------------------------------
template <int ACT, int AF32, int OM0, int OM1, int BM, int BN>
__global__ __launch_bounds__(256) void gemm_bt(
    const void* __restrict__ A0, const void* __restrict__ A1,
    const short* __restrict__ B0, const short* __restrict__ B1,
    const float* __restrict__ b0, const float* __restrict__ b1,
    void* C0_, void* C1_,
    float s0, float s1, int nbn, int N, int K)
{
    constexpr int MT = BM / 32;        // m-tiles per wave
    constexpr int NT = BN / 32;        // n-tiles per wave
    const int z = blockIdx.z;
    const void* A = z ? A1 : A0;
    const short* B = z ? B1 : B0;
    const float* bias = z ? b1 : b0;
    void* C_ = z ? C1_ : C0_;
    const float scale = z ? s1 : s0;
    const int om = z ? OM1 : OM0;

    const int L = blockIdx.x;
    const int xcd = L & 7;
    const int per = L >> 3;
    const int bn = (per % nbn) * BN;
    const int bm = ((per / nbn) * 8 + xcd) * BM;

    const int tid = threadIdx.x;
    const int w = tid >> 6;
    const int lane = tid & 63;
    const int l15 = lane & 15, quad = lane >> 4;
    const int wm = (w >> 1) * (BM / 2), wn = (w & 1) * (BN / 2);

    __shared__ __align__(16) short As[BM * 64];
    __shared__ __align__(16) short Bs[BN * 64];

    f32x4 acc[MT][NT];
#pragma unroll
    for (int mt = 0; mt < MT; ++mt)
#pragma unroll
        for (int nt = 0; nt < NT; ++nt) acc[mt][nt] = (f32x4){0.f, 0.f, 0.f, 0.f};

    for (int k0 = 0; k0 < K; k0 += 64) {
#pragma unroll
        for (int i = 0; i < BM / 32; ++i) {
            int ga = tid + i * 256;
            int row = ga >> 3, g = ga & 7;
            if constexpr (AF32) {
                const float* Af = (const float*)A;
                const float* src = &Af[(size_t)(bm + row) * K + k0 + ((g ^ (row & 7)) * 8)];
                float4 x = *(const float4*)src;
                float4 y = *(const float4*)(src + 4);
                unsigned u0, u1, u2, u3;
                asm("v_cvt_pk_bf16_f32 %0, %1, %2" : "=v"(u0) : "v"(x.x), "v"(x.y));
                asm("v_cvt_pk_bf16_f32 %0, %1, %2" : "=v"(u1) : "v"(x.z), "v"(x.w));
                asm("v_cvt_pk_bf16_f32 %0, %1, %2" : "=v"(u2) : "v"(y.x), "v"(y.y));
                asm("v_cvt_pk_bf16_f32 %0, %1, %2" : "=v"(u3) : "v"(y.z), "v"(y.w));
                uint4v u; u[0] = u0; u[1] = u1; u[2] = u2; u[3] = u3;
                *(uint4v*)(void*)&As[row * 64 + g * 8] = u;
            } else {
                const short* Ab = (const short*)A;
                gload_lds16(&Ab[(size_t)(bm + row) * K + k0 + ((g ^ (row & 7)) * 8)],
                            &As[(i * 256 + w * 64) * 8]);
            }
        }
#pragma unroll
        for (int i = 0; i < BN / 32; ++i) {
            int gb = tid + i * 256;
            int row = gb >> 3, g = gb & 7;
            gload_lds16(&B[(size_t)(bn + row) * K + k0 + ((g ^ (row & 7)) * 8)],
                        &Bs[(i * 256 + w * 64) * 8]);
        }
        __syncthreads();

#pragma unroll
        for (int ks = 0; ks < 2; ++ks) {
            bf16x8 af[MT], bfr[NT];
#pragma unroll
            for (int t = 0; t < MT; ++t) {
                int row = wm + t * 16 + l15;
                af[t] = __builtin_bit_cast(bf16x8,
                    *(const short8*)(const void*)&As[row * 64 + (((ks * 4 + quad) ^ (row & 7)) * 8)]);
            }
#pragma unroll
            for (int t = 0; t < NT; ++t) {
                int row = wn + t * 16 + l15;
                bfr[t] = __builtin_bit_cast(bf16x8,
                    *(const short8*)(const void*)&Bs[row * 64 + (((ks * 4 + quad) ^ (row & 7)) * 8)]);
            }
#pragma unroll
            for (int mt = 0; mt < MT; ++mt)
#pragma unroll
                for (int nt = 0; nt < NT; ++nt)
                    acc[mt][nt] = __builtin_amdgcn_mfma_f32_16x16x32_bf16(af[mt], bfr[nt], acc[mt][nt], 0, 0, 0);
        }
        __syncthreads();
    }

    float bvv[NT];
#pragma unroll
    for (int nt = 0; nt < NT; ++nt) bvv[nt] = bias[bn + wn + nt * 16 + l15];
#pragma unroll
    for (int mt = 0; mt < MT; ++mt)
#pragma unroll
        for (int r = 0; r < 4; ++r) {
            int row = bm + wm + mt * 16 + quad * 4 + r;
#pragma unroll
            for (int nt = 0; nt < NT; ++nt) {
                float v = acc[mt][nt][r] + bvv[nt];
                if (ACT) v = gelu_f(v);
                v *= scale;
                int col = bn + wn + nt * 16 + l15;
                if (om == 1) {
                    ((float*)C_)[(size_t)row * N + col] = v;
                } else if (om == 2) {
                    // kfr scatter: inverse of repack_kv K-path.
                    int b_ = row >> 12, key = row & 4095;
                    int kt = key >> 6, nt_ = (key >> 5) & 1, l31_ = key & 31;
                    int h_ = col >> 5, kcol = col & 31;
                    int ks_ = kcol >> 4, hi_ = (kcol >> 3) & 1, j_ = kcol & 7;
                    size_t idx = ((((size_t)(b_ * 8 + h_) * 64 + kt) * 4 +
                                   (nt_ * 2 + ks_)) * 64 + (hi_ * 32 + l31_)) * 8 + j_;
                    ((short*)C_)[idx] = f2bf(v);
                } else if (om == 3) {
                    // vfr scatter: inverse of repack_kv V-path.
                    int b_ = row >> 12, key = row & 4095;
                    int kt = key >> 6, keyr = key & 63;
                    int ks_ = keyr >> 4, hi_ = (keyr >> 3) & 1, j_ = keyr & 7;
                    int h_ = col >> 6, dk = col & 63;
                    int dt_ = dk >> 5, l31_ = dk & 31;
                    size_t idx = ((((size_t)(b_ * 8 + h_) * 64 + kt) * 8 +
                                   (dt_ * 4 + ks_)) * 64 + (hi_ * 32 + l31_)) * 8 + j_;
                    ((short*)C_)[idx] = f2bf(v);
                } else {
                    ((short*)C_)[(size_t)row * N + col] = f2bf(v);
                }
            }
        }
}

// ---------------------------------------------------------------------------
// Flash attention — R3 proven form, verbatim (71.4 µs, VGPR 64, occ 30%).
// In-register P redistribution (v_permlane32_swap_b32, vdst[32:63]<->
// src0[0:31]), RNE cvt_pk pack, f32 VALU denominator.
// ---------------------------------------------------------------------------
__global__ __launch_bounds__(256, 4) void flash_ks(
    const short* __restrict__ qb, const short* __restrict__ kfr,
    const short* __restrict__ vfr, short* __restrict__ xbb)
{
    const int L = blockIdx.x;          // 0..1023
    const int xcd = L & 7;
    const int idx = L >> 3;            // 0..127
    const int bh = xcd * 2 + (idx & 1);
    const int qt = idx >> 1;           // 0..63: 64 q rows per block
    const int b = bh >> 3, h = bh & 7;
    const int w = threadIdx.x >> 6;
    const int qg = w >> 1;             // q-group 0/1 (32 rows each)
    const int kh = w & 1;              // key-half 0/1
    const int lane = threadIdx.x & 63;
    const int l31 = lane & 31;
    const int half = lane >> 5;

    // smem is ONLY the end-combine: redO [2][32][66] f32 + redl [4][32] f32
    __shared__ __align__(16) char smem[17408];

    const short* qrow = qb + (size_t)(b * 4096 + qt * 64 + qg * 32 + l31) * 256 + h * 32 + half * 8;
    bf16x8 qf0 = __builtin_bit_cast(bf16x8, *(const short8*)(const void*)qrow);
    bf16x8 qf1 = __builtin_bit_cast(bf16x8, *(const short8*)(const void*)(qrow + 16));

    f32x16 O0{}, O1{};
    f32x2 lp = (f32x2){0.f, 0.f};      // denominator pair-accumulator (f32)

    const short* kbase = kfr + ((size_t)bh * 64) * 4 * 512 + lane * 8;
    const short* vbase = vfr + ((size_t)bh * 64) * 8 * 512 + lane * 8;

#pragma unroll 1
    for (int t = 0; t < 32; ++t) {
        const int kt = kh * 32 + t;
        bf16x8 kc[4], vc[8];
        const short* kp = kbase + (size_t)kt * 4 * 512;
        const short* vp = vbase + (size_t)kt * 8 * 512;
#pragma unroll
        for (int c = 0; c < 4; ++c)
            kc[c] = __builtin_bit_cast(bf16x8, *(const short8*)(const void*)(kp + c * 512));
#pragma unroll
        for (int c = 0; c < 8; ++c)
            vc[c] = __builtin_bit_cast(bf16x8, *(const short8*)(const void*)(vp + c * 512));

        f32x16 zero{};
        f32x16 s0 = __builtin_amdgcn_mfma_f32_32x32x16_bf16(kc[0], qf0, zero, 0, 0, 0);
        s0 = __builtin_amdgcn_mfma_f32_32x32x16_bf16(kc[1], qf1, s0, 0, 0, 0);
        f32x16 s1 = __builtin_amdgcn_mfma_f32_32x32x16_bf16(kc[2], qf0, zero, 0, 0, 0);
        s1 = __builtin_amdgcn_mfma_f32_32x32x16_bf16(kc[3], qf1, s1, 0, 0, 0);

        // exp + RNE cvt_pk pack + in-register cross-half redistribution;
        // denominator accumulated as f32 pair-sums (consistent w/ RNE pack).
        bf16x8 pf[4];
#pragma unroll
        for (int nt = 0; nt < 2; ++nt) {
            const f32x16& s = nt ? s1 : s0;
            float p0  = __builtin_amdgcn_exp2f(s[0]);
            float p1  = __builtin_amdgcn_exp2f(s[1]);
            float p2  = __builtin_amdgcn_exp2f(s[2]);
            float p3  = __builtin_amdgcn_exp2f(s[3]);
            float p4  = __builtin_amdgcn_exp2f(s[4]);
            float p5  = __builtin_amdgcn_exp2f(s[5]);
            float p6  = __builtin_amdgcn_exp2f(s[6]);
            float p7  = __builtin_amdgcn_exp2f(s[7]);
            float p8  = __builtin_amdgcn_exp2f(s[8]);
            float p9  = __builtin_amdgcn_exp2f(s[9]);
            float p10 = __builtin_amdgcn_exp2f(s[10]);
            float p11 = __builtin_amdgcn_exp2f(s[11]);
            float p12 = __builtin_amdgcn_exp2f(s[12]);
            float p13 = __builtin_amdgcn_exp2f(s[13]);
            float p14 = __builtin_amdgcn_exp2f(s[14]);
            float p15 = __builtin_amdgcn_exp2f(s[15]);

            lp += (f32x2){p0,  p1};
            lp += (f32x2){p2,  p3};
            lp += (f32x2){p4,  p5};
            lp += (f32x2){p6,  p7};
            lp += (f32x2){p8,  p9};
            lp += (f32x2){p10, p11};
            lp += (f32x2){p12, p13};
            lp += (f32x2){p14, p15};

            unsigned D0, D1, D2, D3, D4, D5, D6, D7;
            asm("v_cvt_pk_bf16_f32 %0, %1, %2" : "=v"(D0) : "v"(p0),  "v"(p1));
            asm("v_cvt_pk_bf16_f32 %0, %1, %2" : "=v"(D1) : "v"(p2),  "v"(p3));
            asm("v_cvt_pk_bf16_f32 %0, %1, %2" : "=v"(D2) : "v"(p4),  "v"(p5));
            asm("v_cvt_pk_bf16_f32 %0, %1, %2" : "=v"(D3) : "v"(p6),  "v"(p7));
            asm("v_cvt_pk_bf16_f32 %0, %1, %2" : "=v"(D4) : "v"(p8),  "v"(p9));
            asm("v_cvt_pk_bf16_f32 %0, %1, %2" : "=v"(D5) : "v"(p10), "v"(p11));
            asm("v_cvt_pk_bf16_f32 %0, %1, %2" : "=v"(D6) : "v"(p12), "v"(p13));
            asm("v_cvt_pk_bf16_f32 %0, %1, %2" : "=v"(D7) : "v"(p14), "v"(p15));
            // vdst_hi <-> src0_lo swaps: after these, (D0,D1,D2,D3) are the
            // 4 dwords of frag ks=2nt, (D4,D5,D6,D7) the dwords of ks=2nt+1.
            asm("v_permlane32_swap_b32 %0, %1" : "+v"(D0), "+v"(D2));
            asm("v_permlane32_swap_b32 %0, %1" : "+v"(D1), "+v"(D3));
            asm("v_permlane32_swap_b32 %0, %1" : "+v"(D4), "+v"(D6));
            asm("v_permlane32_swap_b32 %0, %1" : "+v"(D5), "+v"(D7));
            uint4v u0; u0[0] = D0; u0[1] = D1; u0[2] = D2; u0[3] = D3;
            uint4v u1; u1[0] = D4; u1[1] = D5; u1[2] = D6; u1[3] = D7;
            pf[2 * nt + 0] = __builtin_bit_cast(bf16x8, u0);
            pf[2 * nt + 1] = __builtin_bit_cast(bf16x8, u1);
        }

#pragma unroll
        for (int ks = 0; ks < 4; ++ks) {
            O0 = __builtin_amdgcn_mfma_f32_32x32x16_bf16(pf[ks], vc[ks], O0, 0, 0, 0);
            O1 = __builtin_amdgcn_mfma_f32_32x32x16_bf16(pf[ks], vc[4 + ks], O1, 0, 0, 0);
        }
    }

    // denominator: combine pair-accumulator, then lane halves (h0 + h1).
    float lsum = lp[0] + lp[1];
    float lother = lsum;
    asm("v_permlane32_swap_b32 %0, %1" : "+v"(lsum), "+v"(lother));
    lsum += lother;                    // full per-(qg,kh) sum, every lane

    // ---- combine key-half pairs per q-group ----
    float* redO = (float*)smem;              // [qg][32 q][66] = 16896 B
    float* redl = (float*)(smem + 16896);    // [qg*2+kh][32 q] = 512 B
    if (half == 0)
        redl[(qg * 2 + kh) * 32 + l31] = lsum;
    if (kh == 1) {
        float* Bo = redO + qg * 32 * 66;
#pragma unroll
        for (int r = 0; r < 16; ++r) {
            int q = (r & 3) + 8 * (r >> 2) + 4 * half;
            Bo[q * 66 + l31] = O0[r];
            Bo[q * 66 + 32 + l31] = O1[r];
        }
    }
    __syncthreads();
    if (kh == 0) {
        const float* Bo = redO + qg * 32 * 66;
#pragma unroll
        for (int r = 0; r < 16; ++r) {
            int q = (r & 3) + 8 * (r >> 2) + 4 * half;
            float o0 = O0[r] + Bo[q * 66 + l31];
            float o1 = O1[r] + Bo[q * 66 + 32 + l31];
            float inv = 1.f / (redl[(qg * 2 + 0) * 32 + q] + redl[(qg * 2 + 1) * 32 + q]);
            size_t row = (size_t)(b * 4096 + qt * 64 + qg * 32 + q);
            short* d = xbb + row * 512 + h * 64 + l31;
            d[0] = f2bf(o0 * inv);
            d[32] = f2bf(o1 * inv);
        }
    }
}

// ---------------------------------------------------------------------------
extern "C" void kernel_launch(void* const* d_in, const int* in_sizes, int n_in,
                              void* d_out, int out_size, void* d_ws, size_t ws_size,
                              hipStream_t stream)
{
    const float* query = (const float*)d_in[0];
    const float* key   = (const float*)d_in[1];
    const float* value = (const float*)d_in[2];
    const float* Wq1   = (const float*)d_in[3];
    const float* bq1   = (const float*)d_in[4];
    const float* Wq2   = (const float*)d_in[5];
    const float* bq2   = (const float*)d_in[6];
    const float* Wk1   = (const float*)d_in[7];
    const float* bk1   = (const float*)d_in[8];
    const float* Wk2   = (const float*)d_in[9];
    const float* bk2   = (const float*)d_in[10];
    const float* Wv    = (const float*)d_in[11];
    const float* bv    = (const float*)d_in[12];
    const float* Wo    = (const float*)d_in[13];
    const float* bo    = (const float*)d_in[14];
    float* out = (float*)d_out;

    // Workspace (bytes), overlays:
    char* ws = (char*)d_ws;
    short* H1q   = (short*)(ws + 0);          // 16 MB
    short* H1k   = (short*)(ws + 16777216);   // 16 MB
    short* xbb   = (short*)(ws + 0);          // overlay (H1 dead after gemm2)
    short* qbb   = (short*)(ws + 33554432);   // 4 MB
    short* kfr   = (short*)(ws + 50331648);   // 4 MB
    short* vfr   = (short*)(ws + 54525952);   // 8 MB
    short* Wq1t  = (short*)(ws + 62914560);
    short* Wk1t  = (short*)(ws + 63963136);
    short* Wq2t  = (short*)(ws + 65011712);
    short* Wk2t  = (short*)(ws + 65536000);
    short* Wvt   = (short*)(ws + 66060288);
    short* Wot   = (short*)(ws + 66584576);   // 512 KB -> end 67,108,864

    dim3 blk(256);
    const float qscale = 0.17677669529663687f * 1.4426950408889634f;

    // weight transposes only (input casts fused into GEMM A-staging)
    prep_w<<<dim3(2048), blk, 0, stream>>>(
        Wq1, Wk1, Wq2, Wk2, Wv, Wo, Wq1t, Wk1t, Wq2t, Wk2t, Wvt, Wot);

    // MLP layer 1 (q & k batched): f32-A staging, GELU, bf16 out.
    gemm_bt<1, 1, 0, 0, 128, 128><<<dim3(8 * 64, 1, 2), blk, 0, stream>>>(
        query, key, Wq1t, Wk1t, bq1, bk1, H1q, H1k, 1.f, 1.f, 8, 1024, 512);
    // MLP layer 2 (q & k batched): q -> qbb plain (pre-scaled),
    // k -> kfr frag-major scatter (repack fused).
    gemm_bt<0, 0, 0, 2, 64, 64><<<dim3(4 * 128, 1, 2), blk, 0, stream>>>(
        H1q, H1k, Wq2t, Wk2t, bq2, bk2, qbb, kfr, qscale, 1.f, 4, 256, 1024);
    // v projection: f32-A staging, -> vfr frag-major scatter (repack fused).
    gemm_bt<0, 1, 3, 3, 64, 64><<<dim3(8 * 128, 1, 1), blk, 0, stream>>>(
        value, value, Wvt, Wvt, bv, bv, vfr, vfr, 1.f, 1.f, 8, 512, 512);
    // attention: flash with in-register P redistribution, VALU denominator
    flash_ks<<<dim3(1024), blk, 0, stream>>>(qbb, kfr, vfr, xbb);
    // output projection -> f32
    gemm_bt<0, 0, 1, 1, 64, 64><<<dim3(8 * 128, 1, 1), blk, 0, stream>>>(
        xbb, xbb, Wot, Wot, bo, bo, out, out, 1.f, 1.f, 8, 512, 512);
}